// Round 13
// baseline (275.626 us; speedup 1.0000x reference)
//
#include <hip/hip_runtime.h>

typedef __attribute__((ext_vector_type(8))) short bf16x8;
typedef __attribute__((ext_vector_type(4))) short short4v;
typedef __attribute__((ext_vector_type(4))) float f32x4;
typedef __attribute__((ext_vector_type(16))) float f32x16;

#define D_MODEL 1024
#define SEQ 2048
#define BATCH 4
#define NHEAD 16

__device__ __forceinline__ short f2bf(float f) {
  union { float f; unsigned u; } a; a.f = f;
  unsigned r = a.u + 0x7fffu + ((a.u >> 16) & 1u);
  return (short)(r >> 16);
}

__device__ __forceinline__ float bf2f(short s) {
  union { float f; unsigned u; } a; a.u = ((unsigned)(unsigned short)s) << 16;
  return a.f;
}

__device__ __forceinline__ void async16(const void* g, void* l) {
  typedef const __attribute__((address_space(1))) unsigned GT;
  typedef __attribute__((address_space(3))) unsigned LT;
  __builtin_amdgcn_global_load_lds((GT*)g, (LT*)l, 16, 0, 0);
}

// ------- weight transpose + bf16 convert (all 4 weights in one launch) -------
__global__ void wprep_kernel(const float* __restrict__ W0, const float* __restrict__ W1,
                             const float* __restrict__ W2, const float* __restrict__ W3,
                             short* __restrict__ Wt) {
  __shared__ short t[32][33];
  const int z = blockIdx.z;
  const float* W = (z == 0) ? W0 : (z == 1) ? W1 : (z == 2) ? W2 : W3;
  short* out = Wt + (size_t)z * 1024 * 1024;
  int tx = threadIdx.x, ty = threadIdx.y;
  int n = blockIdx.x * 32 + tx, k = blockIdx.y * 32 + ty;
  t[ty][tx] = f2bf(W[(size_t)k * 1024 + n]);
  __syncthreads();
  int nn = blockIdx.x * 32 + ty, kk = blockIdx.y * 32 + tx;
  out[(size_t)nn * 1024 + kk] = t[tx][ty];
}

// ---------------- f32 -> bf16 elementwise, two tensors in one launch ----------
__global__ void cvt_bf16_kernel(const float* __restrict__ inA, const float* __restrict__ inB,
                                short* __restrict__ outA, short* __restrict__ outB, int n4each) {
  int idx = blockIdx.x * blockDim.x + threadIdx.x;
  int stride = gridDim.x * blockDim.x;
  for (int i = idx; i < 2 * n4each; i += stride) {
    const float* in = (i < n4each) ? inA : inB;
    short* out = (i < n4each) ? outA : outB;
    int j = (i < n4each) ? i : i - n4each;
    float4 v = ((const float4*)in)[j];
    short4v o; o[0] = f2bf(v.x); o[1] = f2bf(v.y); o[2] = f2bf(v.z); o[3] = f2bf(v.w);
    ((short4v*)out)[j] = o;
  }
}

// ---- GEMM: C = A(bf16)[M,K] * Bt(bf16)[N,K]^T + bias.  BM=BN=128, BK=64 ----
// 256 threads / 4 waves (2Mx2N), dbuf LDS (64KB -> 2 blocks/CU), counted-vmcnt
// 2-deep prefetch (vmcnt(8)), T2 XOR swizzle, T5 setprio.
// MODE 4: Cb row-major bf16 (Q-proj).
// MODE 5: KV stacked (N=2048, same A for both halves):
//         col<1024  -> Cb  = kt4 chunk-major [B][H][S/64][8 d-ch][64 kv][8], *SCL
//         col>=1024 -> Cb2 = vt4 chunk-major [B][H][S/64][8 kv-ch][64 d][8], +bias2
// MODE 2: Cb = bf16( bf2f(residb) + relu(acc + bias) )  (output GEMM)
template<int MODE>
__global__ __launch_bounds__(256)
void gemm_kernel(const short* __restrict__ A, const short* __restrict__ Bt,
                 const float* __restrict__ bias, const float* __restrict__ bias2,
                 const short* __restrict__ residb,
                 short* __restrict__ Cb, short* __restrict__ Cb2,
                 int M, int N, int K, float SCL, int nbx) {
  __shared__ short lA[2][128 * 64];
  __shared__ short lB[2][128 * 64];
  const int tid = threadIdx.x;
  const int lane = tid & 63;
  const int wid = tid >> 6;
  const int wr = wid >> 1, wc = wid & 1;

  // bijective XCD swizzle (grid is a multiple of 8)
  const int cpx = gridDim.x >> 3;
  const int swz = (blockIdx.x & 7) * cpx + (blockIdx.x >> 3);
  const int m0 = (swz / nbx) * 128, n0 = (swz % nbx) * 128;

  const int lr8 = lane >> 3;
  const int lc8s = ((lane & 7) ^ lr8) * 8;  // pre-swizzled source column (shorts)
  const int lr16 = lane & 15, lhi = lane >> 4;
  const int xk = (lr16 & 7) << 3;           // read-side XOR (shorts)

  f32x4 acc[4][4];
  const f32x4 zf = {0.f, 0.f, 0.f, 0.f};
#pragma unroll
  for (int i = 0; i < 4; ++i)
#pragma unroll
    for (int j = 0; j < 4; ++j) acc[i][j] = zf;

  const int NTK = K >> 6;

#define GSTAGE(T, BUF)                                                          \
  do {                                                                          \
    int k0 = (T) * 64;                                                          \
    _Pragma("unroll")                                                           \
    for (int c = 0; c < 4; ++c) {                                               \
      int i = wid * 4 + c;                                                      \
      async16(A + (size_t)(m0 + 8 * i + lr8) * K + k0 + lc8s,                   \
              (void*)(&lA[BUF][i * 512]));                                      \
      async16(Bt + (size_t)(n0 + 8 * i + lr8) * K + k0 + lc8s,                  \
              (void*)(&lB[BUF][i * 512]));                                      \
    }                                                                           \
  } while (0)

  GSTAGE(0, 0);
  GSTAGE(1, 1);

  for (int t = 0; t < NTK; ++t) {
    if (t + 1 < NTK) asm volatile("s_waitcnt vmcnt(8)" ::: "memory");
    else             asm volatile("s_waitcnt vmcnt(0)" ::: "memory");
    __builtin_amdgcn_s_barrier();   // all waves' tile-t loads landed
    const short* At_ = lA[t & 1];
    const short* Bt_ = lB[t & 1];
#pragma unroll
    for (int ks = 0; ks < 2; ++ks) {
      const int kcol = (ks * 32 + lhi * 8) ^ xk;
      bf16x8 af[4], bfr[4];
#pragma unroll
      for (int mi = 0; mi < 4; ++mi)
        af[mi] = *(const bf16x8*)&At_[(wr * 64 + mi * 16 + lr16) * 64 + kcol];
#pragma unroll
      for (int ni = 0; ni < 4; ++ni)
        bfr[ni] = *(const bf16x8*)&Bt_[(wc * 64 + ni * 16 + lr16) * 64 + kcol];
      __builtin_amdgcn_s_setprio(1);
#pragma unroll
      for (int mi = 0; mi < 4; ++mi)
#pragma unroll
        for (int ni = 0; ni < 4; ++ni)
          acc[mi][ni] = __builtin_amdgcn_mfma_f32_16x16x32_bf16(af[mi], bfr[ni], acc[mi][ni], 0, 0, 0);
      __builtin_amdgcn_s_setprio(0);
    }
    __builtin_amdgcn_s_barrier();   // all waves done reading buf[t&1]
    if (t + 2 < NTK) GSTAGE(t + 2, t & 1);
  }
#undef GSTAGE

#pragma unroll
  for (int mi = 0; mi < 4; ++mi) {
#pragma unroll
    for (int ni = 0; ni < 4; ++ni) {
      int col = n0 + wc * 64 + ni * 16 + lr16;
#pragma unroll
      for (int r = 0; r < 4; ++r) {
        int row = m0 + wr * 64 + mi * 16 + lhi * 4 + r;
        if (MODE == 4) {
          float v = acc[mi][ni][r] + bias[col];
          Cb[(size_t)row * N + col] = f2bf(v);
        }
        if (MODE == 2) {
          size_t off = (size_t)row * N + col;
          float v = acc[mi][ni][r] + bias[col];
          Cb[off] = f2bf(bf2f(residb[off]) + fmaxf(v, 0.f));
        }
        if (MODE == 5) {
          int bb = row >> 11, s = row & 2047, tt = s >> 6;
          if (col < 1024) {
            float v = acc[mi][ni][r] + bias[col];
            int rr = s & 63, h = col >> 6, d = col & 63;
            size_t idx = ((((size_t)(bb * 16 + h) * 32 + tt) * 8 + (d >> 3)) * 64 + rr) * 8 + (d & 7);
            Cb[idx] = f2bf(v * SCL);
          } else {
            int dd = col - 1024;
            float v = acc[mi][ni][r] + bias2[dd];
            int h = dd >> 6, d = dd & 63;
            size_t idx = ((((size_t)(bb * 16 + h) * 32 + tt) * 8 + ((s & 63) >> 3)) * 64 + d) * 8 + (s & 7);
            Cb2[idx] = f2bf(v);
          }
        }
      }
    }
  }
}

// ---------------- flash attention + residual(q), BARRIER-FREE streaming -------
// grid: 512 linear blocks (XCD-swizzled), 256 threads, 64 q-rows per wave
// (2 q-groups of 32). NO LDS: K/V fragments read directly from global (chunk-
// major layout makes every frag a coalesced 1KB/wave read; per-(b,h) K/V =
// 512KB, 8 consumer blocks co-located per XCD -> L2-resident). K-frags
// prefetched 1 tile ahead into named reg buffers (kfA/kfB, static indexing);
// V-frags on demand (latency hides under softmax chain). Waves free-run.
// K pre-scaled by (1/32)*log2(e). Denominator: VALU partial sums + shfl_xor(32).
__global__ __launch_bounds__(256)
void attn_kernel(const short* __restrict__ qb, const short* __restrict__ kt4,
                 const short* __restrict__ vt4, short* __restrict__ O1b) {
  const int tid = threadIdx.x;
  const int lane = tid & 63;
  const int wid = tid >> 6;

  const int flat = blockIdx.x;
  const int w = (flat & 7) * 64 + (flat >> 3);   // bijective 512 = 8*64
  const int qblk = w & 7, hh = (w >> 3) & 15, b = w >> 7;
  const int q0w = qblk * 256 + wid * 64;         // wave's 64 q-rows

  const int lr32 = lane & 31, lhi32 = lane >> 5;
  const size_t baseB = (size_t)b * SEQ * D_MODEL;

  // Q as B-fragment, two q-groups: col=q0w+g*32+(lane&31), k=d=ks*16+lhi32*8+j
  bf16x8 qA[2][4];
#pragma unroll
  for (int g = 0; g < 2; ++g)
#pragma unroll
    for (int ks = 0; ks < 4; ++ks)
      qA[g][ks] = *(const bf16x8*)&qb[baseB + (size_t)(q0w + g * 32 + lr32) * D_MODEL + hh * 64 + ks * 16 + lhi32 * 8];

  // per-lane frag offsets within one 4096-short tile (chunk-major)
  int kfo[2][4];   // K: chunk = ks*2+lhi32, row = cb*32 + lr32
#pragma unroll
  for (int cb = 0; cb < 2; ++cb)
#pragma unroll
    for (int ks = 0; ks < 4; ++ks)
      kfo[cb][ks] = (ks * 2 + lhi32) * 512 + (cb * 32 + lr32) * 8;
  int vfo[2][4];   // V^T: chunk = cbp*2+lhi32, row = ni*32 + lr32
#pragma unroll
  for (int ni = 0; ni < 2; ++ni)
#pragma unroll
    for (int cbp = 0; cbp < 4; ++cbp)
      vfo[ni][cbp] = (cbp * 2 + lhi32) * 512 + (ni * 32 + lr32) * 8;

  const size_t tbase = (size_t)(b * 16 + hh) * 32 * 4096;
  const short* kT = kt4 + tbase;
  const short* vT = vt4 + tbase;

  f32x16 accO[2][2];
  float lsump[2] = {0.f, 0.f};
#pragma unroll
  for (int r = 0; r < 16; ++r) {
    accO[0][0][r] = 0.f; accO[0][1][r] = 0.f;
    accO[1][0][r] = 0.f; accO[1][1][r] = 0.f;
  }

  const int NT = SEQ / 64;

#define LOADK(DST, TPTR)                                                       \
  do {                                                                         \
    _Pragma("unroll")                                                          \
    for (int cb_ = 0; cb_ < 2; ++cb_)                                          \
      _Pragma("unroll")                                                        \
      for (int ks_ = 0; ks_ < 4; ++ks_)                                        \
        DST[cb_][ks_] = *(const bf16x8*)&(TPTR)[kfo[cb_][ks_]];                \
  } while (0)

#define ATT_TILE(KF, VPTR)                                                     \
  do {                                                                         \
    _Pragma("unroll")                                                          \
    for (int cb = 0; cb < 2; ++cb) {                                           \
      f32x16 s0, s1;                                                           \
      _Pragma("unroll")                                                        \
      for (int r = 0; r < 16; ++r) { s0[r] = 0.f; s1[r] = 0.f; }               \
      __builtin_amdgcn_s_setprio(1);                                           \
      _Pragma("unroll")                                                        \
      for (int ks = 0; ks < 4; ++ks) {                                         \
        s0 = __builtin_amdgcn_mfma_f32_32x32x16_bf16(KF[cb][ks], qA[0][ks], s0, 0, 0, 0); \
        s1 = __builtin_amdgcn_mfma_f32_32x32x16_bf16(KF[cb][ks], qA[1][ks], s1, 0, 0, 0); \
      }                                                                        \
      __builtin_amdgcn_s_setprio(0);                                           \
      float p[2][16];                                                          \
      _Pragma("unroll")                                                        \
      for (int r = 0; r < 16; ++r) {                                           \
        p[0][r] = __builtin_amdgcn_exp2f(s0[r]);                               \
        p[1][r] = __builtin_amdgcn_exp2f(s1[r]);                               \
      }                                                                        \
      _Pragma("unroll")                                                        \
      for (int g = 0; g < 2; ++g) {                                            \
        float f0 = 0.f, f1 = 0.f;                                              \
        _Pragma("unroll")                                                      \
        for (int r = 0; r < 8; ++r) { f0 += p[g][2 * r]; f1 += p[g][2 * r + 1]; } \
        lsump[g] += f0 + f1;                                                   \
      }                                                                        \
      unsigned wd[2][8];                                                       \
      _Pragma("unroll")                                                        \
      for (int g = 0; g < 2; ++g)                                              \
        _Pragma("unroll")                                                      \
        for (int gq = 0; gq < 4; ++gq)                                         \
          _Pragma("unroll")                                                    \
          for (int w2 = 0; w2 < 2; ++w2) {                                     \
            unsigned o;                                                        \
            asm("v_cvt_pk_bf16_f32 %0, %1, %2" : "=v"(o)                       \
                : "v"(p[g][4 * gq + 2 * w2]), "v"(p[g][4 * gq + 2 * w2 + 1])); \
            wd[g][gq * 2 + w2] = o;                                            \
          }                                                                    \
      _Pragma("unroll")                                                        \
      for (int c1 = 0; c1 < 2; ++c1) {                                         \
        const int cbp = 2 * cb + c1;                                           \
        bf16x8 vf0 = *(const bf16x8*)&(VPTR)[vfo[0][cbp]];                     \
        bf16x8 vf1 = *(const bf16x8*)&(VPTR)[vfo[1][cbp]];                     \
        __builtin_amdgcn_s_setprio(1);                                         \
        _Pragma("unroll")                                                      \
        for (int g = 0; g < 2; ++g) {                                          \
          unsigned a0 = wd[g][(2 * c1) * 2 + 0], b0 = wd[g][(2 * c1 + 1) * 2 + 0]; \
          unsigned a1 = wd[g][(2 * c1) * 2 + 1], b1 = wd[g][(2 * c1 + 1) * 2 + 1]; \
          asm("v_permlane32_swap_b32 %0, %1" : "+v"(a0), "+v"(b0));            \
          asm("v_permlane32_swap_b32 %0, %1" : "+v"(a1), "+v"(b1));            \
          union { unsigned u[4]; bf16x8 v; } pb;                               \
          pb.u[0] = a0; pb.u[1] = a1; pb.u[2] = b0; pb.u[3] = b1;              \
          accO[g][0] = __builtin_amdgcn_mfma_f32_32x32x16_bf16(vf0, pb.v, accO[g][0], 0, 0, 0); \
          accO[g][1] = __builtin_amdgcn_mfma_f32_32x32x16_bf16(vf1, pb.v, accO[g][1], 0, 0, 0); \
        }                                                                      \
        __builtin_amdgcn_s_setprio(0);                                         \
      }                                                                        \
    }                                                                          \
  } while (0)

  bf16x8 kfA[2][4], kfB[2][4];
  LOADK(kfA, kT);

  for (int t = 0; t < NT; t += 2) {
    LOADK(kfB, kT + (size_t)(t + 1) * 4096);
    ATT_TILE(kfA, vT + (size_t)t * 4096);
    if (t + 2 < NT) LOADK(kfA, kT + (size_t)(t + 2) * 4096);
    ATT_TILE(kfB, vT + (size_t)(t + 1) * 4096);
  }
#undef LOADK
#undef ATT_TILE

  // denominator: lanes l and l+32 hold the same q-column
#pragma unroll
  for (int g = 0; g < 2; ++g) {
    float tot = lsump[g] + __shfl_xor(lsump[g], 32);
    float inv = 1.f / tot;
    const int qrow = q0w + g * 32 + lr32;
    const short* qbp2 = qb + baseB + (size_t)qrow * D_MODEL + hh * 64;
    short* o1p = O1b + baseB + (size_t)qrow * D_MODEL + hh * 64;
#pragma unroll
    for (int ni = 0; ni < 2; ++ni)
#pragma unroll
      for (int gq = 0; gq < 4; ++gq) {
        int col = ni * 32 + 8 * gq + 4 * lhi32;
        short4v qs = *(const short4v*)&qbp2[col];
        short4v ov;
#pragma unroll
        for (int j = 0; j < 4; ++j)
          ov[j] = f2bf(bf2f(qs[j]) + accO[g][ni][4 * gq + j] * inv);
        *(short4v*)&o1p[col] = ov;
      }
  }
}

// ---------------- row LayerNorm (D=1024) --------------------------------------
// IN_BF: input bf16 (short*) else f32. OUT_BF: write bf16 Yb only, else f32 Yf.
template<int IN_BF, int OUT_BF>
__global__ __launch_bounds__(256)
void ln_kernel(const void* __restrict__ Xv, const float* __restrict__ g,
               const float* __restrict__ be, float* __restrict__ Yf,
               short* __restrict__ Yb) {
  const int tid = threadIdx.x;
  const size_t row = blockIdx.x;
  float4 v;
  if (IN_BF) {
    short4v xs = ((const short4v*)Xv)[row * 256 + tid];
    v.x = bf2f(xs[0]); v.y = bf2f(xs[1]); v.z = bf2f(xs[2]); v.w = bf2f(xs[3]);
  } else {
    v = ((const float4*)Xv)[row * 256 + tid];
  }
  float s = v.x + v.y + v.z + v.w;
  float s2 = v.x * v.x + v.y * v.y + v.z * v.z + v.w * v.w;
#pragma unroll
  for (int msk = 1; msk < 64; msk <<= 1) { s += __shfl_xor(s, msk); s2 += __shfl_xor(s2, msk); }
  __shared__ float rs[4], rs2[4];
  if ((tid & 63) == 0) { rs[tid >> 6] = s; rs2[tid >> 6] = s2; }
  __syncthreads();
  s = rs[0] + rs[1] + rs[2] + rs[3];
  s2 = rs2[0] + rs2[1] + rs2[2] + rs2[3];
  float mu = s * (1.f / 1024.f);
  float rstd = rsqrtf(s2 * (1.f / 1024.f) - mu * mu + 1e-5f);
  float4 gv = ((const float4*)g)[tid];
  float4 bv = ((const float4*)be)[tid];
  float4 y;
  y.x = (v.x - mu) * rstd * gv.x + bv.x;
  y.y = (v.y - mu) * rstd * gv.y + bv.y;
  y.z = (v.z - mu) * rstd * gv.z + bv.z;
  y.w = (v.w - mu) * rstd * gv.w + bv.w;
  if (OUT_BF) {
    short4v o; o[0] = f2bf(y.x); o[1] = f2bf(y.y); o[2] = f2bf(y.z); o[3] = f2bf(y.w);
    ((short4v*)(Yb + row * 1024))[tid] = o;
  } else {
    ((float4*)(Yf + row * 1024))[tid] = y;
  }
}

extern "C" void kernel_launch(void* const* d_in, const int* in_sizes, int n_in,
                              void* d_out, int out_size, void* d_ws, size_t ws_size,
                              hipStream_t stream) {
  const float* Q  = (const float*)d_in[0];
  const float* K  = (const float*)d_in[1];
  const float* Wq = (const float*)d_in[2];
  const float* bq = (const float*)d_in[3];
  const float* Wk = (const float*)d_in[4];
  const float* bk = (const float*)d_in[5];
  const float* Wv = (const float*)d_in[6];
  const float* bv = (const float*)d_in[7];
  const float* Wo = (const float*)d_in[8];
  const float* bo = (const float*)d_in[9];
  const float* g0 = (const float*)d_in[10];
  const float* b0 = (const float*)d_in[11];
  const float* g1 = (const float*)d_in[12];
  const float* b1 = (const float*)d_in[13];

  char* ws = (char*)d_ws;
  const size_t MB = 1024 * 1024;
  short* Wt  = (short*)(ws + 0);         // Wqt,Wkt,Wvt,Wot (8MB bytes)
  short* Qb  = (short*)(ws + 8 * MB);    // 16MB (dead after Q-proj)
  short* Kb  = (short*)(ws + 24 * MB);   // 16MB (dead after KV gemm)
  short* qbp = (short*)(ws + 40 * MB);   // 16MB bf16 Q-proj
  short* kt4 = (short*)(ws + 56 * MB);   // 16MB K chunk-major (*SCL)
  short* Vt4 = (short*)(ws + 72 * MB);   // 16MB V^T chunk-major
  short* O1b = (short*)(ws + 8 * MB);    // bf16 attn out (reuse Qb)
  short* Xb  = (short*)(ws + 152 * MB);  // bf16 LN1 out
  short* Yb2 = (short*)(ws + 24 * MB);   // bf16 gemm2 out (reuse Kb)
  float* Y   = (float*)d_out;

  const int Mrows = BATCH * SEQ;  // 8192
  const float SCL = 0.03125f * 1.44269504f;  // (1/32) * log2(e), folded into K

  wprep_kernel<<<dim3(32, 32, 4), dim3(32, 32), 0, stream>>>(Wq, Wk, Wv, Wo, Wt);

  cvt_bf16_kernel<<<2048, 256, 0, stream>>>(Q, K, Qb, Kb, Mrows * 1024 / 4);

  // Q projection: C row-major bf16
  gemm_kernel<4><<<512, 256, 0, stream>>>(Qb, Wt, bq, nullptr, nullptr,
                                          qbp, nullptr, Mrows, 1024, 1024, 1.0f, 8);
  // K+V fused (shared A = Kb, stacked weights [Wkt;Wvt], N=2048)
  gemm_kernel<5><<<1024, 256, 0, stream>>>(Kb, Wt + (1 << 20), bk, bv, nullptr,
                                           kt4, Vt4, Mrows, 2048, 1024, SCL, 16);

  attn_kernel<<<512, 256, 0, stream>>>(qbp, kt4, Vt4, O1b);

  ln_kernel<1, 1><<<Mrows, 256, 0, stream>>>(O1b, g0, b0, nullptr, Xb);

  gemm_kernel<2><<<512, 256, 0, stream>>>(Xb, Wt + 3 * (1 << 20), bo, nullptr, Xb,
                                          Yb2, nullptr, Mrows, 1024, 1024, 1.0f, 8);

  ln_kernel<1, 0><<<Mrows, 256, 0, stream>>>(Yb2, g1, b1, Y, nullptr);
}

// Round 14
// 234.362 us; speedup vs baseline: 1.1761x; 1.1761x over previous
//
#include <hip/hip_runtime.h>

typedef __attribute__((ext_vector_type(8))) short bf16x8;
typedef __attribute__((ext_vector_type(4))) short short4v;
typedef __attribute__((ext_vector_type(4))) float f32x4;
typedef __attribute__((ext_vector_type(16))) float f32x16;

#define D_MODEL 1024
#define SEQ 2048
#define BATCH 4
#define NHEAD 16

__device__ __forceinline__ short f2bf(float f) {
  union { float f; unsigned u; } a; a.f = f;
  unsigned r = a.u + 0x7fffu + ((a.u >> 16) & 1u);
  return (short)(r >> 16);
}

__device__ __forceinline__ float bf2f(short s) {
  union { float f; unsigned u; } a; a.u = ((unsigned)(unsigned short)s) << 16;
  return a.f;
}

__device__ __forceinline__ void async16(const void* g, void* l) {
  typedef const __attribute__((address_space(1))) unsigned GT;
  typedef __attribute__((address_space(3))) unsigned LT;
  __builtin_amdgcn_global_load_lds((GT*)g, (LT*)l, 16, 0, 0);
}

// ------- weight transpose + bf16 convert (all 4 weights in one launch) -------
__global__ void wprep_kernel(const float* __restrict__ W0, const float* __restrict__ W1,
                             const float* __restrict__ W2, const float* __restrict__ W3,
                             short* __restrict__ Wt) {
  __shared__ short t[32][33];
  const int z = blockIdx.z;
  const float* W = (z == 0) ? W0 : (z == 1) ? W1 : (z == 2) ? W2 : W3;
  short* out = Wt + (size_t)z * 1024 * 1024;
  int tx = threadIdx.x, ty = threadIdx.y;
  int n = blockIdx.x * 32 + tx, k = blockIdx.y * 32 + ty;
  t[ty][tx] = f2bf(W[(size_t)k * 1024 + n]);
  __syncthreads();
  int nn = blockIdx.x * 32 + ty, kk = blockIdx.y * 32 + tx;
  out[(size_t)nn * 1024 + kk] = t[tx][ty];
}

// ---------------- f32 -> bf16 elementwise, two tensors in one launch ----------
__global__ void cvt_bf16_kernel(const float* __restrict__ inA, const float* __restrict__ inB,
                                short* __restrict__ outA, short* __restrict__ outB, int n4each) {
  int idx = blockIdx.x * blockDim.x + threadIdx.x;
  int stride = gridDim.x * blockDim.x;
  for (int i = idx; i < 2 * n4each; i += stride) {
    const float* in = (i < n4each) ? inA : inB;
    short* out = (i < n4each) ? outA : outB;
    int j = (i < n4each) ? i : i - n4each;
    float4 v = ((const float4*)in)[j];
    short4v o; o[0] = f2bf(v.x); o[1] = f2bf(v.y); o[2] = f2bf(v.z); o[3] = f2bf(v.w);
    ((short4v*)out)[j] = o;
  }
}

// ---- GEMM: C = A(bf16)[M,K] * Bt(bf16)[N,K]^T + bias.  BM=BN=128, BK=64 ----
// 256 threads / 4 waves (2Mx2N), dbuf LDS (64KB -> 2 blocks/CU), counted-vmcnt
// 2-deep prefetch (vmcnt(8)), T2 XOR swizzle, T5 setprio.
// MODE 4: Cb row-major bf16 (Q-proj).
// MODE 5: KV stacked (N=2048, same A for both halves):
//         col<1024  -> Cb  = kt4 chunk-major [B][H][S/64][8 d-ch][64 kv][8], *SCL
//         col>=1024 -> Cb2 = vt4 chunk-major [B][H][S/64][8 kv-ch][64 d][8], +bias2
// MODE 2: Cb = bf16( bf2f(residb) + relu(acc + bias) )  (output GEMM)
template<int MODE>
__global__ __launch_bounds__(256)
void gemm_kernel(const short* __restrict__ A, const short* __restrict__ Bt,
                 const float* __restrict__ bias, const float* __restrict__ bias2,
                 const short* __restrict__ residb,
                 short* __restrict__ Cb, short* __restrict__ Cb2,
                 int M, int N, int K, float SCL, int nbx) {
  __shared__ short lA[2][128 * 64];
  __shared__ short lB[2][128 * 64];
  const int tid = threadIdx.x;
  const int lane = tid & 63;
  const int wid = tid >> 6;
  const int wr = wid >> 1, wc = wid & 1;

  // bijective XCD swizzle (grid is a multiple of 8)
  const int cpx = gridDim.x >> 3;
  const int swz = (blockIdx.x & 7) * cpx + (blockIdx.x >> 3);
  const int m0 = (swz / nbx) * 128, n0 = (swz % nbx) * 128;

  const int lr8 = lane >> 3;
  const int lc8s = ((lane & 7) ^ lr8) * 8;  // pre-swizzled source column (shorts)
  const int lr16 = lane & 15, lhi = lane >> 4;
  const int xk = (lr16 & 7) << 3;           // read-side XOR (shorts)

  f32x4 acc[4][4];
  const f32x4 zf = {0.f, 0.f, 0.f, 0.f};
#pragma unroll
  for (int i = 0; i < 4; ++i)
#pragma unroll
    for (int j = 0; j < 4; ++j) acc[i][j] = zf;

  const int NTK = K >> 6;

#define GSTAGE(T, BUF)                                                          \
  do {                                                                          \
    int k0 = (T) * 64;                                                          \
    _Pragma("unroll")                                                           \
    for (int c = 0; c < 4; ++c) {                                               \
      int i = wid * 4 + c;                                                      \
      async16(A + (size_t)(m0 + 8 * i + lr8) * K + k0 + lc8s,                   \
              (void*)(&lA[BUF][i * 512]));                                      \
      async16(Bt + (size_t)(n0 + 8 * i + lr8) * K + k0 + lc8s,                  \
              (void*)(&lB[BUF][i * 512]));                                      \
    }                                                                           \
  } while (0)

  GSTAGE(0, 0);
  GSTAGE(1, 1);

  for (int t = 0; t < NTK; ++t) {
    if (t + 1 < NTK) asm volatile("s_waitcnt vmcnt(8)" ::: "memory");
    else             asm volatile("s_waitcnt vmcnt(0)" ::: "memory");
    __builtin_amdgcn_s_barrier();   // all waves' tile-t loads landed
    const short* At_ = lA[t & 1];
    const short* Bt_ = lB[t & 1];
#pragma unroll
    for (int ks = 0; ks < 2; ++ks) {
      const int kcol = (ks * 32 + lhi * 8) ^ xk;
      bf16x8 af[4], bfr[4];
#pragma unroll
      for (int mi = 0; mi < 4; ++mi)
        af[mi] = *(const bf16x8*)&At_[(wr * 64 + mi * 16 + lr16) * 64 + kcol];
#pragma unroll
      for (int ni = 0; ni < 4; ++ni)
        bfr[ni] = *(const bf16x8*)&Bt_[(wc * 64 + ni * 16 + lr16) * 64 + kcol];
      __builtin_amdgcn_s_setprio(1);
#pragma unroll
      for (int mi = 0; mi < 4; ++mi)
#pragma unroll
        for (int ni = 0; ni < 4; ++ni)
          acc[mi][ni] = __builtin_amdgcn_mfma_f32_16x16x32_bf16(af[mi], bfr[ni], acc[mi][ni], 0, 0, 0);
      __builtin_amdgcn_s_setprio(0);
    }
    __builtin_amdgcn_s_barrier();   // all waves done reading buf[t&1]
    if (t + 2 < NTK) GSTAGE(t + 2, t & 1);
  }
#undef GSTAGE

#pragma unroll
  for (int mi = 0; mi < 4; ++mi) {
#pragma unroll
    for (int ni = 0; ni < 4; ++ni) {
      int col = n0 + wc * 64 + ni * 16 + lr16;
#pragma unroll
      for (int r = 0; r < 4; ++r) {
        int row = m0 + wr * 64 + mi * 16 + lhi * 4 + r;
        if (MODE == 4) {
          float v = acc[mi][ni][r] + bias[col];
          Cb[(size_t)row * N + col] = f2bf(v);
        }
        if (MODE == 2) {
          size_t off = (size_t)row * N + col;
          float v = acc[mi][ni][r] + bias[col];
          Cb[off] = f2bf(bf2f(residb[off]) + fmaxf(v, 0.f));
        }
        if (MODE == 5) {
          int bb = row >> 11, s = row & 2047, tt = s >> 6;
          if (col < 1024) {
            float v = acc[mi][ni][r] + bias[col];
            int rr = s & 63, h = col >> 6, d = col & 63;
            size_t idx = ((((size_t)(bb * 16 + h) * 32 + tt) * 8 + (d >> 3)) * 64 + rr) * 8 + (d & 7);
            Cb[idx] = f2bf(v * SCL);
          } else {
            int dd = col - 1024;
            float v = acc[mi][ni][r] + bias2[dd];
            int h = dd >> 6, d = dd & 63;
            size_t idx = ((((size_t)(bb * 16 + h) * 32 + tt) * 8 + ((s & 63) >> 3)) * 64 + d) * 8 + (s & 7);
            Cb2[idx] = f2bf(v);
          }
        }
      }
    }
  }
}

// ---------------- flash attention + residual(q) -------------------------------
// grid: 512 linear blocks (XCD-swizzled), 256 threads, 64 q-rows per wave
// (2 q-groups of 32 -> 2x dependency-chain ILP). KVBLK=128: each staged
// super-tile holds TWO 64-row chunk-major sub-tiles (32KB K+V), halving the
// barrier/vmcnt count vs KVBLK=64. Double-buffered (64KB LDS), counted-vmcnt
// 2-deep prefetch (8 loads/super-tile/wave -> vmcnt(8)).
// K pre-scaled by (1/32)*log2(e). 32x32x16 MFMA swapped operands; P via
// cvt_pk_bf16 + permlane32_swap; ones-MFMA denominator.
__global__ __launch_bounds__(256)
void attn_kernel(const short* __restrict__ qb, const short* __restrict__ kt4,
                 const short* __restrict__ vt4, short* __restrict__ O1b) {
  __shared__ short lK[2][2 * 4096];
  __shared__ short lV[2][2 * 4096];
  const int tid = threadIdx.x;
  const int lane = tid & 63;
  const int wid = tid >> 6;

  const int flat = blockIdx.x;
  const int w = (flat & 7) * 64 + (flat >> 3);   // bijective 512 = 8*64
  const int qblk = w & 7, hh = (w >> 3) & 15, b = w >> 7;
  const int q0w = qblk * 256 + wid * 64;         // wave's 64 q-rows

  const int lr32 = lane & 31, lhi32 = lane >> 5;
  const size_t baseB = (size_t)b * SEQ * D_MODEL;

  // Q as B-fragment, two q-groups: col=q0w+g*32+(lane&31), k=d=ks*16+lhi32*8+j
  bf16x8 qA[2][4];
#pragma unroll
  for (int g = 0; g < 2; ++g)
#pragma unroll
    for (int ks = 0; ks < 4; ++ks)
      qA[g][ks] = *(const bf16x8*)&qb[baseB + (size_t)(q0w + g * 32 + lr32) * D_MODEL + hh * 64 + ks * 16 + lhi32 * 8];

  bf16x8 onesA;
#pragma unroll
  for (int j = 0; j < 8; ++j) onesA[j] = (short)0x3F80;

  // per-sub-tile chunk-major offsets (shorts), lane-contiguous
  int kOff[2][4];   // K: chunk = ks*2+lhi32, row = cb*32 + lr32
#pragma unroll
  for (int cb = 0; cb < 2; ++cb)
#pragma unroll
    for (int ks = 0; ks < 4; ++ks)
      kOff[cb][ks] = (ks * 2 + lhi32) * 512 + (cb * 32 + lr32) * 8;
  int vOff[2][4];   // V^T: chunk = cbp*2+lhi32, row = ni*32 + lr32
#pragma unroll
  for (int ni = 0; ni < 2; ++ni)
#pragma unroll
    for (int cbp = 0; cbp < 4; ++cbp)
      vOff[ni][cbp] = (cbp * 2 + lhi32) * 512 + (ni * 32 + lr32) * 8;

  // staging: per super-tile (128 kv) 16 chunks K + 16 V; wave stages 4 each
  const size_t tbase = (size_t)(b * 16 + hh) * 32 * 4096;
  const short* kSrc = kt4 + tbase + (size_t)(wid * 4) * 512 + lane * 8;
  const short* vSrc = vt4 + tbase + (size_t)(wid * 4) * 512 + lane * 8;

  f32x16 accO[2][2], accS[2];
#pragma unroll
  for (int r = 0; r < 16; ++r) {
    accO[0][0][r] = 0.f; accO[0][1][r] = 0.f;
    accO[1][0][r] = 0.f; accO[1][1][r] = 0.f;
    accS[0][r] = 0.f; accS[1][r] = 0.f;
  }

  const int NT2 = SEQ / 128;   // 16 super-tiles

#define STAGE(T, BUF)                                                        \
  do {                                                                       \
    size_t toff = (size_t)(T) * 8192;                                        \
    _Pragma("unroll")                                                        \
    for (int c = 0; c < 4; ++c) {                                            \
      async16(kSrc + toff + c * 512, (void*)(&lK[BUF][(wid * 4 + c) * 512]));\
      async16(vSrc + toff + c * 512, (void*)(&lV[BUF][(wid * 4 + c) * 512]));\
    }                                                                        \
  } while (0)

  STAGE(0, 0);
  STAGE(1, 1);

  for (int t = 0; t < NT2; ++t) {
    if (t + 1 < NT2) asm volatile("s_waitcnt vmcnt(8)" ::: "memory");
    else             asm volatile("s_waitcnt vmcnt(0)" ::: "memory");
    __builtin_amdgcn_s_barrier();   // all waves' super-tile-t loads landed

#pragma unroll
    for (int st = 0; st < 2; ++st) {
      const short* Kb_ = &lK[t & 1][st * 4096];
      const short* Vb_ = &lV[t & 1][st * 4096];

#pragma unroll
      for (int cb = 0; cb < 2; ++cb) {
        f32x16 s0, s1;
#pragma unroll
        for (int r = 0; r < 16; ++r) { s0[r] = 0.f; s1[r] = 0.f; }
#pragma unroll
        for (int ks = 0; ks < 4; ++ks) {
          bf16x8 kf = *(const bf16x8*)&Kb_[kOff[cb][ks]];
          s0 = __builtin_amdgcn_mfma_f32_32x32x16_bf16(kf, qA[0][ks], s0, 0, 0, 0);
          s1 = __builtin_amdgcn_mfma_f32_32x32x16_bf16(kf, qA[1][ks], s1, 0, 0, 0);
        }

        float p[2][16];
#pragma unroll
        for (int r = 0; r < 16; ++r) {
          p[0][r] = __builtin_amdgcn_exp2f(s0[r]);
          p[1][r] = __builtin_amdgcn_exp2f(s1[r]);
        }

        unsigned wd[2][8];
#pragma unroll
        for (int g = 0; g < 2; ++g)
#pragma unroll
          for (int gq = 0; gq < 4; ++gq)
#pragma unroll
            for (int w2 = 0; w2 < 2; ++w2) {
              unsigned o;
              asm("v_cvt_pk_bf16_f32 %0, %1, %2" : "=v"(o)
                  : "v"(p[g][4 * gq + 2 * w2]), "v"(p[g][4 * gq + 2 * w2 + 1]));
              wd[g][gq * 2 + w2] = o;
            }

#pragma unroll
        for (int c1 = 0; c1 < 2; ++c1) {
          const int cbp = 2 * cb + c1;
          bf16x8 vf0 = *(const bf16x8*)&Vb_[vOff[0][cbp]];
          bf16x8 vf1 = *(const bf16x8*)&Vb_[vOff[1][cbp]];
#pragma unroll
          for (int g = 0; g < 2; ++g) {
            unsigned a0 = wd[g][(2 * c1) * 2 + 0], b0 = wd[g][(2 * c1 + 1) * 2 + 0];
            unsigned a1 = wd[g][(2 * c1) * 2 + 1], b1 = wd[g][(2 * c1 + 1) * 2 + 1];
            asm("v_permlane32_swap_b32 %0, %1" : "+v"(a0), "+v"(b0));
            asm("v_permlane32_swap_b32 %0, %1" : "+v"(a1), "+v"(b1));
            union { unsigned u[4]; bf16x8 v; } pb;
            pb.u[0] = a0; pb.u[1] = a1; pb.u[2] = b0; pb.u[3] = b1;
            accO[g][0] = __builtin_amdgcn_mfma_f32_32x32x16_bf16(vf0, pb.v, accO[g][0], 0, 0, 0);
            accO[g][1] = __builtin_amdgcn_mfma_f32_32x32x16_bf16(vf1, pb.v, accO[g][1], 0, 0, 0);
            accS[g] = __builtin_amdgcn_mfma_f32_32x32x16_bf16(onesA, pb.v, accS[g], 0, 0, 0);
          }
        }
      }
    }
    __builtin_amdgcn_s_barrier();   // all waves done reading buf[t&1]
    if (t + 2 < NT2) STAGE(t + 2, t & 1);
  }
#undef STAGE

#pragma unroll
  for (int g = 0; g < 2; ++g) {
    float inv = 1.f / accS[g][0];
    const int qrow = q0w + g * 32 + lr32;
    const short* qbp2 = qb + baseB + (size_t)qrow * D_MODEL + hh * 64;
    short* o1p = O1b + baseB + (size_t)qrow * D_MODEL + hh * 64;
#pragma unroll
    for (int ni = 0; ni < 2; ++ni)
#pragma unroll
      for (int gq = 0; gq < 4; ++gq) {
        int col = ni * 32 + 8 * gq + 4 * lhi32;
        short4v qs = *(const short4v*)&qbp2[col];
        short4v ov;
#pragma unroll
        for (int j = 0; j < 4; ++j)
          ov[j] = f2bf(bf2f(qs[j]) + accO[g][ni][4 * gq + j] * inv);
        *(short4v*)&o1p[col] = ov;
      }
  }
}

// ---------------- row LayerNorm (D=1024) --------------------------------------
// IN_BF: input bf16 (short*) else f32. OUT_BF: write bf16 Yb only, else f32 Yf.
template<int IN_BF, int OUT_BF>
__global__ __launch_bounds__(256)
void ln_kernel(const void* __restrict__ Xv, const float* __restrict__ g,
               const float* __restrict__ be, float* __restrict__ Yf,
               short* __restrict__ Yb) {
  const int tid = threadIdx.x;
  const size_t row = blockIdx.x;
  float4 v;
  if (IN_BF) {
    short4v xs = ((const short4v*)Xv)[row * 256 + tid];
    v.x = bf2f(xs[0]); v.y = bf2f(xs[1]); v.z = bf2f(xs[2]); v.w = bf2f(xs[3]);
  } else {
    v = ((const float4*)Xv)[row * 256 + tid];
  }
  float s = v.x + v.y + v.z + v.w;
  float s2 = v.x * v.x + v.y * v.y + v.z * v.z + v.w * v.w;
#pragma unroll
  for (int msk = 1; msk < 64; msk <<= 1) { s += __shfl_xor(s, msk); s2 += __shfl_xor(s2, msk); }
  __shared__ float rs[4], rs2[4];
  if ((tid & 63) == 0) { rs[tid >> 6] = s; rs2[tid >> 6] = s2; }
  __syncthreads();
  s = rs[0] + rs[1] + rs[2] + rs[3];
  s2 = rs2[0] + rs2[1] + rs2[2] + rs2[3];
  float mu = s * (1.f / 1024.f);
  float rstd = rsqrtf(s2 * (1.f / 1024.f) - mu * mu + 1e-5f);
  float4 gv = ((const float4*)g)[tid];
  float4 bv = ((const float4*)be)[tid];
  float4 y;
  y.x = (v.x - mu) * rstd * gv.x + bv.x;
  y.y = (v.y - mu) * rstd * gv.y + bv.y;
  y.z = (v.z - mu) * rstd * gv.z + bv.z;
  y.w = (v.w - mu) * rstd * gv.w + bv.w;
  if (OUT_BF) {
    short4v o; o[0] = f2bf(y.x); o[1] = f2bf(y.y); o[2] = f2bf(y.z); o[3] = f2bf(y.w);
    ((short4v*)(Yb + row * 1024))[tid] = o;
  } else {
    ((float4*)(Yf + row * 1024))[tid] = y;
  }
}

extern "C" void kernel_launch(void* const* d_in, const int* in_sizes, int n_in,
                              void* d_out, int out_size, void* d_ws, size_t ws_size,
                              hipStream_t stream) {
  const float* Q  = (const float*)d_in[0];
  const float* K  = (const float*)d_in[1];
  const float* Wq = (const float*)d_in[2];
  const float* bq = (const float*)d_in[3];
  const float* Wk = (const float*)d_in[4];
  const float* bk = (const float*)d_in[5];
  const float* Wv = (const float*)d_in[6];
  const float* bv = (const float*)d_in[7];
  const float* Wo = (const float*)d_in[8];
  const float* bo = (const float*)d_in[9];
  const float* g0 = (const float*)d_in[10];
  const float* b0 = (const float*)d_in[11];
  const float* g1 = (const float*)d_in[12];
  const float* b1 = (const float*)d_in[13];

  char* ws = (char*)d_ws;
  const size_t MB = 1024 * 1024;
  short* Wt  = (short*)(ws + 0);         // Wqt,Wkt,Wvt,Wot (8MB bytes)
  short* Qb  = (short*)(ws + 8 * MB);    // 16MB (dead after Q-proj)
  short* Kb  = (short*)(ws + 24 * MB);   // 16MB (dead after KV gemm)
  short* qbp = (short*)(ws + 40 * MB);   // 16MB bf16 Q-proj
  short* kt4 = (short*)(ws + 56 * MB);   // 16MB K chunk-major (*SCL)
  short* Vt4 = (short*)(ws + 72 * MB);   // 16MB V^T chunk-major
  short* O1b = (short*)(ws + 8 * MB);    // bf16 attn out (reuse Qb)
  short* Xb  = (short*)(ws + 152 * MB);  // bf16 LN1 out
  short* Yb2 = (short*)(ws + 24 * MB);   // bf16 gemm2 out (reuse Kb)
  float* Y   = (float*)d_out;

  const int Mrows = BATCH * SEQ;  // 8192
  const float SCL = 0.03125f * 1.44269504f;  // (1/32) * log2(e), folded into K

  wprep_kernel<<<dim3(32, 32, 4), dim3(32, 32), 0, stream>>>(Wq, Wk, Wv, Wo, Wt);

  cvt_bf16_kernel<<<2048, 256, 0, stream>>>(Q, K, Qb, Kb, Mrows * 1024 / 4);

  // Q projection: C row-major bf16
  gemm_kernel<4><<<512, 256, 0, stream>>>(Qb, Wt, bq, nullptr, nullptr,
                                          qbp, nullptr, Mrows, 1024, 1024, 1.0f, 8);
  // K+V fused (shared A = Kb, stacked weights [Wkt;Wvt], N=2048)
  gemm_kernel<5><<<1024, 256, 0, stream>>>(Kb, Wt + (1 << 20), bk, bv, nullptr,
                                           kt4, Vt4, Mrows, 2048, 1024, SCL, 16);

  attn_kernel<<<512, 256, 0, stream>>>(qbp, kt4, Vt4, O1b);

  ln_kernel<1, 1><<<Mrows, 256, 0, stream>>>(O1b, g0, b0, nullptr, Xb);

  gemm_kernel<2><<<512, 256, 0, stream>>>(Xb, Wt + 3 * (1 << 20), bo, nullptr, Xb,
                                          Yb2, nullptr, Mrows, 1024, 1024, 1.0f, 8);

  ln_kernel<1, 0><<<Mrows, 256, 0, stream>>>(Yb2, g1, b1, Y, nullptr);
}